// Round 11
// baseline (171.549 us; speedup 1.0000x reference)
//
#include <hip/hip_runtime.h>
#include <stdint.h>

#define MARGIN 0.2f
#define INF_BITS 0x7F800000u

typedef __attribute__((ext_vector_type(8))) short bfrag;     // 8 bf16 (4 VGPRs)
typedef __attribute__((ext_vector_type(4))) float f32x4;

__device__ __forceinline__ unsigned short f32_to_bf16(float f) {
  unsigned u = __float_as_uint(f);
  u += 0x7FFFu + ((u >> 16) & 1u);   // RNE
  return (unsigned short)(u >> 16);
}

// ---------------- Phase 0: norms, d_ap, bf16 conversion, min-init ----------------
// one wave per row (4 rows/block)
__global__ __launch_bounds__(256) void prep_kernel(
    const float* __restrict__ anchor, const float* __restrict__ positive,
    const float* __restrict__ negative,
    unsigned short* __restrict__ a_bf, unsigned short* __restrict__ n_bf,
    float* __restrict__ a2, float* __restrict__ n2, float* __restrict__ dap,
    unsigned* __restrict__ gsh, unsigned* __restrict__ gv, int D) {
  const int wid  = threadIdx.x >> 6;
  const int lane = threadIdx.x & 63;
  const int row  = blockIdx.x * 4 + wid;
  const size_t base = (size_t)row * D;
  const int epl = D >> 6;            // elements per lane (8 for D=512)
  const int k0  = lane * epl;
  float sa2 = 0.f, sdap = 0.f, sn2 = 0.f;

  for (int c = 0; c < epl; c += 8) {
    const float4* ap = (const float4*)(anchor   + base + k0 + c);
    const float4* pp = (const float4*)(positive + base + k0 + c);
    const float4* np = (const float4*)(negative + base + k0 + c);
    float4 a0 = ap[0], a1 = ap[1];
    float4 p0 = pp[0], p1 = pp[1];
    float4 v0 = np[0], v1 = np[1];
    float aa[8] = {a0.x,a0.y,a0.z,a0.w,a1.x,a1.y,a1.z,a1.w};
    float pv[8] = {p0.x,p0.y,p0.z,p0.w,p1.x,p1.y,p1.z,p1.w};
    float nn[8] = {v0.x,v0.y,v0.z,v0.w,v1.x,v1.y,v1.z,v1.w};
    #pragma unroll
    for (int e = 0; e < 8; e++) {
      sa2 += aa[e] * aa[e];
      float dd = aa[e] - pv[e];
      sdap += dd * dd;
      sn2 += nn[e] * nn[e];
    }
    unsigned au[4], nu[4];
    #pragma unroll
    for (int e = 0; e < 4; e++) {
      au[e] = (unsigned)f32_to_bf16(aa[2*e]) | ((unsigned)f32_to_bf16(aa[2*e+1]) << 16);
      nu[e] = (unsigned)f32_to_bf16(nn[2*e]) | ((unsigned)f32_to_bf16(nn[2*e+1]) << 16);
    }
    *(uint4*)(a_bf + base + k0 + c) = make_uint4(au[0], au[1], au[2], au[3]);
    *(uint4*)(n_bf + base + k0 + c) = make_uint4(nu[0], nu[1], nu[2], nu[3]);
  }
  #pragma unroll
  for (int off = 32; off > 0; off >>= 1) {
    sa2  += __shfl_down(sa2,  off);
    sdap += __shfl_down(sdap, off);
    sn2  += __shfl_down(sn2,  off);
  }
  if (lane == 0) {
    a2[row]  = sa2;
    dap[row] = sdap;
    n2[row]  = sn2;
    gsh[row] = INF_BITS;
    gv[row]  = INF_BITS;
  }
}

// ---------------- Phase 1: bf16 MFMA GEMM + fused semihard-min epilogue ----------
// R6 structure + R11 delta: B operand direct global->register (no LDS for B).
//  - Profile at R6 optimum: LDS pipe ~52% busy (39% reads + 13% staging writes),
//    VALU 42%, MFMA 28% -> LDS traffic is the biggest non-MFMA consumer.
//  - B fragments are 16B/lane, 16B-aligned in global: load straight to VGPRs.
//    LDS reads halve (8 ds_read_b128/wave-step), staging halves (4 gload_lds,
//    A only), B-load latency overlaps A-staging (same pre-MFMA drain point).
//  - B read 2x from L2 (both wave-columns) - L2-resident, FETCH unaffected.
// 128x128 tile, BK=64, 4 waves (2x2), T2 A-swizzle, 2D-chunked XCD swizzle.
__global__ __launch_bounds__(256, 4) void gemm_min_kernel(
    const unsigned short* __restrict__ a_bf, const unsigned short* __restrict__ n_bf,
    const float* __restrict__ a2, const float* __restrict__ n2,
    const float* __restrict__ dap, const int* __restrict__ ta, const int* __restrict__ tn,
    unsigned* __restrict__ gsh, unsigned* __restrict__ gv, int D, int nj) {
  __shared__ unsigned short ldsA[128 * 64];   // [row][64 bf16] = 128B/row, 16KB
  __shared__ unsigned lds_msh[128];
  __shared__ unsigned lds_mv[128];

  const int tid  = threadIdx.x;
  const int lane = tid & 63;
  const int wid  = tid >> 6;
  const int wr   = wid >> 1, wc = wid & 1;   // 2x2 wave grid, 64x64 per wave
  const int lg   = lane >> 4;                // 0..3 (K-group within frag)
  const int lc   = lane & 15;                // 0..15 (row within frag)

  // ---- 2D-chunked XCD swizzle (R6-proven) ----
  const int bid = (int)blockIdx.x;
  int it, jt;
  if ((nj & 7) == 0) {
    const int band = nj >> 3;            // i-tiles per XCD (8 for N=8192)
    const int xcd  = bid & 7;
    const int l    = bid >> 3;           // local index within XCD [0, nj*band)
    const int q    = l / (band * 8);     // j super-square index [0, nj/8)
    const int s    = l - q * (band * 8); // [0, band*8)
    it = xcd * band + (s >> 3);
    jt = q * 8 + (s & 7);
  } else {                               // fallback: 1D bijective swizzle
    const int wg = (bid & 7) * ((int)gridDim.x >> 3) + (bid >> 3);
    it = wg / nj; jt = wg % nj;
  }
  const int i0 = it * 128;
  const int j0 = jt * 128;

  if (tid < 128) { lds_msh[tid] = INF_BITS; lds_mv[tid] = INF_BITS; }

  // A staging (4 instrs x 4KB = 16KB): instr c covers rows c*32 + (tid>>3),
  // phys slot tid&7, swizzled source col (rule #21). LDS dest lane-linear.
  const int srow = tid >> 3;                       // 0..31 (row within 32-chunk)
  const int scol = (((tid & 7) ^ (srow & 7)) << 3);// swizzled source col (elems)
  unsigned aBase[4];
  #pragma unroll
  for (int c = 0; c < 4; c++)
    aBase[c] = (unsigned)((i0 + c * 32 + srow) * D + scol);

  // B direct-to-reg: per-lane fragment base (row j, k-subcol lg*8), 32-bit
  unsigned bBase[4];
  #pragma unroll
  for (int n = 0; n < 4; n++)
    bBase[n] = (unsigned)((j0 + wc * 64 + n * 16 + lc) * D + lg * 8);

  f32x4 acc[4][4];
  #pragma unroll
  for (int m = 0; m < 4; m++)
    #pragma unroll
    for (int n = 0; n < 4; n++)
      acc[m][n] = (f32x4){0.f, 0.f, 0.f, 0.f};

  const int ps0 = lg ^ (lc & 7);   // A phys slot for kk=0; kk=1 is ps0^4

  for (int kc = 0; kc < D; kc += 64) {
    __syncthreads();   // previous K-step's A reads done before overwrite
    // stage A (4 x 4KB) and load B fragments (8 x 16B/lane) - both drain below
    #pragma unroll
    for (int c = 0; c < 4; c++) {
      __builtin_amdgcn_global_load_lds(
          (const __attribute__((address_space(1))) void*)(a_bf + aBase[c] + kc),
          (__attribute__((address_space(3))) void*)(ldsA + c * 2048 + (tid << 3)),
          16, 0, 0);
    }
    bfrag bF[4][2];
    #pragma unroll
    for (int n = 0; n < 4; n++)
      #pragma unroll
      for (int kk = 0; kk < 2; kk++)
        bF[n][kk] = *(const bfrag*)(n_bf + bBase[n] + kc + kk * 32);
    __syncthreads();   // drains vmcnt: A tile in LDS, B frags in regs

    #pragma unroll
    for (int kk = 0; kk < 2; kk++) {
      const int ps = (kk == 0) ? ps0 : (ps0 ^ 4);
      bfrag aF[4];
      #pragma unroll
      for (int m = 0; m < 4; m++)
        aF[m] = *(const bfrag*)(ldsA + (wr*64 + m*16 + lc) * 64 + (ps << 3));
      #pragma unroll
      for (int m = 0; m < 4; m++)
        #pragma unroll
        for (int n = 0; n < 4; n++)
          acc[m][n] = __builtin_amdgcn_mfma_f32_16x16x32_bf16(aF[m], bF[n][kk], acc[m][n], 0, 0, 0);
    }
  }

  // ---- fused epilogue: d = a2[i] + n2[j] - 2*dot; masks; row-min ----
  float n2c[4], thrc[4];
  int tnc[4];
  const int jb = j0 + wc * 64;
  #pragma unroll
  for (int n = 0; n < 4; n++) {
    const int j = jb + n * 16 + lc;
    n2c[n]  = n2[j];
    tnc[n]  = tn[j];
    thrc[n] = dap[j] + MARGIN;   // column-indexed d_ap[j], replicating reference
  }
  #pragma unroll
  for (int m = 0; m < 4; m++) {
    #pragma unroll
    for (int r = 0; r < 4; r++) {
      const int il = wr*64 + m*16 + lg*4 + r;   // C row = (lane>>4)*4 + reg (m89-verified)
      const int i  = i0 + il;
      const float a2i = a2[i];
      const int   tai = ta[i];
      float mv = __uint_as_float(INF_BITS);
      float ms = mv;
      #pragma unroll
      for (int n = 0; n < 4; n++) {
        float d = a2i + n2c[n] - 2.0f * acc[m][n][r];
        bool valid = (tai != tnc[n]);
        if (valid) {
          mv = fminf(mv, d);
          if (d > thrc[n]) ms = fminf(ms, d);
        }
      }
      #pragma unroll
      for (int off = 1; off <= 8; off <<= 1) {  // min over 16-lane column group
        mv = fminf(mv, __shfl_xor(mv, off));
        ms = fminf(ms, __shfl_xor(ms, off));
      }
      if (lc == 0) {   // positive floats: uint order == float order
        atomicMin(&lds_mv[il],  __float_as_uint(mv));
        atomicMin(&lds_msh[il], __float_as_uint(ms));
      }
    }
  }

  __syncthreads();
  if (tid < 128) {
    atomicMin(&gv[i0 + tid],  lds_mv[tid]);
    atomicMin(&gsh[i0 + tid], lds_msh[tid]);
  }
}

// ---------------- Phase 2: d_an select + mean(relu), vectorized ----------------
__global__ __launch_bounds__(256) void finalize_kernel(
    const float* __restrict__ dap, const unsigned* __restrict__ gsh,
    const unsigned* __restrict__ gv, float* __restrict__ out, int n) {
  __shared__ float red[4];
  float s = 0.f;
  const uint4*  g4 = (const uint4*)gsh;
  const uint4*  v4 = (const uint4*)gv;
  const float4* d4 = (const float4*)dap;
  const int nv = n >> 2;                      // 2048 vec4 groups
  for (int i = threadIdx.x; i < nv; i += 256) {
    const uint4  us = g4[i];
    const uint4  uv = v4[i];
    const float4 dd = d4[i];
    const unsigned su[4] = {us.x, us.y, us.z, us.w};
    const unsigned vu[4] = {uv.x, uv.y, uv.z, uv.w};
    const float    df[4] = {dd.x, dd.y, dd.z, dd.w};
    #pragma unroll
    for (int e = 0; e < 4; e++) {
      const unsigned b = (su[e] == INF_BITS) ? vu[e] : su[e];   // semihard else hardest
      const float dan = __uint_as_float(b);
      s += fmaxf(df[e] - dan + MARGIN, 0.f);
    }
  }
  #pragma unroll
  for (int off = 32; off > 0; off >>= 1) s += __shfl_down(s, off);
  if ((threadIdx.x & 63) == 0) red[threadIdx.x >> 6] = s;
  __syncthreads();
  if (threadIdx.x == 0) out[0] = (red[0] + red[1] + red[2] + red[3]) / (float)n;
}

extern "C" void kernel_launch(void* const* d_in, const int* in_sizes, int n_in,
                              void* d_out, int out_size, void* d_ws, size_t ws_size,
                              hipStream_t stream) {
  const float* anchor   = (const float*)d_in[0];
  const float* positive = (const float*)d_in[1];
  const float* negative = (const float*)d_in[2];
  const int*   ta       = (const int*)d_in[3];
  const int*   tn       = (const int*)d_in[4];
  const int N = in_sizes[3];
  const int D = in_sizes[0] / N;

  // workspace layout
  unsigned short* a_bf = (unsigned short*)d_ws;                 // N*D bf16
  unsigned short* n_bf = a_bf + (size_t)N * D;                  // N*D bf16
  float* a2  = (float*)(n_bf + (size_t)N * D);                  // N f32
  float* n2  = a2 + N;
  float* dap = n2 + N;
  unsigned* gsh = (unsigned*)(dap + N);                         // N u32 (min bits)
  unsigned* gv  = gsh + N;
  const size_t needed = (size_t)N * D * 4 + (size_t)N * 20;
  if (ws_size < needed) return;  // deterministic failure signature if ws too small

  const int nj  = N / 128;
  const int nwg = nj * nj;   // 4096 for N=8192; % 8 == 0

  prep_kernel<<<N / 4, 256, 0, stream>>>(anchor, positive, negative,
                                         a_bf, n_bf, a2, n2, dap, gsh, gv, D);
  gemm_min_kernel<<<nwg, 256, 0, stream>>>(a_bf, n_bf, a2, n2, dap,
                                           ta, tn, gsh, gv, D, nj);
  finalize_kernel<<<1, 256, 0, stream>>>(dap, gsh, gv, (float*)d_out, N);
}

// Round 12
// 86.185 us; speedup vs baseline: 1.9905x; 1.9905x over previous
//
#include <hip/hip_runtime.h>
#include <stdint.h>

#define MARGIN 0.2f
#define INF_BITS 0x7F800000u

typedef __attribute__((ext_vector_type(8))) int   i32x8;   // fp8 MFMA operand (32B)
typedef __attribute__((ext_vector_type(4))) float f32x4;

// ---------------- Phase 0: norms, d_ap, fp8 e4m3 conversion, min-init ------------
// one wave per row (4 rows/block). Only the GEMM operands are quantized (fp8);
// a2/n2/d_ap stay exact f32, so distance error comes solely from the dot.
__global__ __launch_bounds__(256) void prep_kernel(
    const float* __restrict__ anchor, const float* __restrict__ positive,
    const float* __restrict__ negative,
    unsigned char* __restrict__ a_f8, unsigned char* __restrict__ n_f8,
    float* __restrict__ a2, float* __restrict__ n2, float* __restrict__ dap,
    unsigned* __restrict__ gsh, unsigned* __restrict__ gv, int D) {
  const int wid  = threadIdx.x >> 6;
  const int lane = threadIdx.x & 63;
  const int row  = blockIdx.x * 4 + wid;
  const size_t base = (size_t)row * D;
  const int epl = D >> 6;            // elements per lane (8 for D=512)
  const int k0  = lane * epl;
  float sa2 = 0.f, sdap = 0.f, sn2 = 0.f;

  for (int c = 0; c < epl; c += 8) {
    const float4* ap = (const float4*)(anchor   + base + k0 + c);
    const float4* pp = (const float4*)(positive + base + k0 + c);
    const float4* np = (const float4*)(negative + base + k0 + c);
    float4 a0 = ap[0], a1 = ap[1];
    float4 p0 = pp[0], p1 = pp[1];
    float4 v0 = np[0], v1 = np[1];
    float aa[8] = {a0.x,a0.y,a0.z,a0.w,a1.x,a1.y,a1.z,a1.w};
    float pv[8] = {p0.x,p0.y,p0.z,p0.w,p1.x,p1.y,p1.z,p1.w};
    float nn[8] = {v0.x,v0.y,v0.z,v0.w,v1.x,v1.y,v1.z,v1.w};
    #pragma unroll
    for (int e = 0; e < 8; e++) {
      sa2 += aa[e] * aa[e];
      float dd = aa[e] - pv[e];
      sdap += dd * dd;
      sn2 += nn[e] * nn[e];
    }
    // pack 8 f32 -> 8 fp8 e4m3 (OCP, RNE) via v_cvt_pk_fp8_f32
    unsigned alo = (unsigned)__builtin_amdgcn_cvt_pk_fp8_f32(aa[0], aa[1], 0, false);
    alo          = (unsigned)__builtin_amdgcn_cvt_pk_fp8_f32(aa[2], aa[3], alo, true);
    unsigned ahi = (unsigned)__builtin_amdgcn_cvt_pk_fp8_f32(aa[4], aa[5], 0, false);
    ahi          = (unsigned)__builtin_amdgcn_cvt_pk_fp8_f32(aa[6], aa[7], ahi, true);
    unsigned nlo = (unsigned)__builtin_amdgcn_cvt_pk_fp8_f32(nn[0], nn[1], 0, false);
    nlo          = (unsigned)__builtin_amdgcn_cvt_pk_fp8_f32(nn[2], nn[3], nlo, true);
    unsigned nhi = (unsigned)__builtin_amdgcn_cvt_pk_fp8_f32(nn[4], nn[5], 0, false);
    nhi          = (unsigned)__builtin_amdgcn_cvt_pk_fp8_f32(nn[6], nn[7], nhi, true);
    *(uint2*)(a_f8 + base + k0 + c) = make_uint2(alo, ahi);
    *(uint2*)(n_f8 + base + k0 + c) = make_uint2(nlo, nhi);
  }
  #pragma unroll
  for (int off = 32; off > 0; off >>= 1) {
    sa2  += __shfl_down(sa2,  off);
    sdap += __shfl_down(sdap, off);
    sn2  += __shfl_down(sn2,  off);
  }
  if (lane == 0) {
    a2[row]  = sa2;
    dap[row] = sdap;
    n2[row]  = sn2;
    gsh[row] = INF_BITS;
    gv[row]  = INF_BITS;
  }
}

// ---------------- Phase 1: fp8 MX-MFMA GEMM + fused semihard-min epilogue --------
// R6 structure, dtype lever: mfma_scale_f32_16x16x128_f8f6f4 (K=128/instr) with
// unity e8m0 scales (0x7F = 2^0; data is N(0,1), inside e4m3 range, so unity
// scales lose nothing). BK=128 fp8: LDS = 2 x 16KB, 4 blocks/CU, but only
// nt = 4 K-steps -> 16 rounds/CU vs bf16's 32 (the round-count invariant breaks
// only via dtype: staged bytes per MFMA-FLOP halve). m148 measured +64% for
// exactly this move on the m97-like structure.
// A/B frag: row = lane&15, k = (lane>>4)*32 + e (32 contiguous bytes, 8 VGPRs);
// C/D layout shape-determined, identical to bf16 (m121-128) -> epilogue reused.
// T2 both-sides XOR swizzle at 16B slots (8 slots/128B row, key = row&7).
__global__ __launch_bounds__(256, 4) void gemm_min_kernel(
    const unsigned char* __restrict__ a_f8, const unsigned char* __restrict__ n_f8,
    const float* __restrict__ a2, const float* __restrict__ n2,
    const float* __restrict__ dap, const int* __restrict__ ta, const int* __restrict__ tn,
    unsigned* __restrict__ gsh, unsigned* __restrict__ gv, int D, int nj) {
  __shared__ unsigned char ldsA[128 * 128];   // [row][128 fp8] = 128B/row, 16KB
  __shared__ unsigned char ldsB[128 * 128];
  __shared__ unsigned lds_msh[128];
  __shared__ unsigned lds_mv[128];

  const int tid  = threadIdx.x;
  const int lane = tid & 63;
  const int wid  = tid >> 6;
  const int wr   = wid >> 1, wc = wid & 1;   // 2x2 wave grid, 64x64 per wave
  const int lg   = lane >> 4;                // 0..3 (K-block of 32 within frag)
  const int lc   = lane & 15;                // 0..15 (row within frag)

  // ---- 2D-chunked XCD swizzle (R6-proven; fp8 panels are 2x smaller) ----
  const int bid = (int)blockIdx.x;
  int it, jt;
  if ((nj & 7) == 0) {
    const int band = nj >> 3;            // i-tiles per XCD (8 for N=8192)
    const int xcd  = bid & 7;
    const int l    = bid >> 3;
    const int q    = l / (band * 8);
    const int s    = l - q * (band * 8);
    it = xcd * band + (s >> 3);
    jt = q * 8 + (s & 7);
  } else {
    const int wg = (bid & 7) * ((int)gridDim.x >> 3) + (bid >> 3);
    it = wg / nj; jt = wg % nj;
  }
  const int i0 = it * 128;
  const int j0 = jt * 128;

  if (tid < 128) { lds_msh[tid] = INF_BITS; lds_mv[tid] = INF_BITS; }

  // staging: 8 gload_lds instrs (4 A + 4 B), each wave writes base + lane*16.
  // instr c, wave wid covers rows c*32 + wid*8 + (lane>>3), phys slot lane&7;
  // source col = (slot ^ (row&7))*16 bytes (rule #21 both-sides swizzle).
  const int srow8 = lane >> 3;                      // 0..7 == row&7 for this lane
  const int scolB = ((lane & 7) ^ srow8) << 4;      // swizzled source col (bytes)
  unsigned aBase[4], bBase[4];
  #pragma unroll
  for (int c = 0; c < 4; c++) {
    const int ro = c * 32 + wid * 8 + srow8;
    aBase[c] = (unsigned)((i0 + ro) * D + scolB);
    bBase[c] = (unsigned)((j0 + ro) * D + scolB);
  }

  f32x4 acc[4][4];
  #pragma unroll
  for (int m = 0; m < 4; m++)
    #pragma unroll
    for (int n = 0; n < 4; n++)
      acc[m][n] = (f32x4){0.f, 0.f, 0.f, 0.f};

  const int nt = D >> 7;   // 4 K-steps of 128

  for (int t = 0; t < nt; ++t) {
    const int kc = t << 7;
    __syncthreads();   // previous K-step's reads done before overwrite
    #pragma unroll
    for (int c = 0; c < 4; c++) {
      __builtin_amdgcn_global_load_lds(
          (const __attribute__((address_space(1))) void*)(a_f8 + aBase[c] + kc),
          (__attribute__((address_space(3))) void*)(ldsA + c * 4096 + wid * 1024),
          16, 0, 0);
      __builtin_amdgcn_global_load_lds(
          (const __attribute__((address_space(1))) void*)(n_f8 + bBase[c] + kc),
          (__attribute__((address_space(3))) void*)(ldsB + c * 4096 + wid * 1024),
          16, 0, 0);
    }
    __syncthreads();   // drains vmcnt -> LDS ready

    // fragment reads: row r, k-block lg -> log slots {2lg, 2lg+1}, phys = ^ (r&7)
    i32x8 bF[4];
    #pragma unroll
    for (int n = 0; n < 4; n++) {
      const int r  = wc * 64 + n * 16 + lc;
      const int p0 = ((lg << 1) ^ (r & 7)) << 4;        // p1 = p0 ^ 16
      const int4 lo = *(const int4*)(ldsB + r * 128 + p0);
      const int4 hi = *(const int4*)(ldsB + r * 128 + (p0 ^ 16));
      bF[n] = (i32x8){lo.x, lo.y, lo.z, lo.w, hi.x, hi.y, hi.z, hi.w};
    }
    #pragma unroll
    for (int m = 0; m < 4; m++) {
      const int r  = wr * 64 + m * 16 + lc;
      const int p0 = ((lg << 1) ^ (r & 7)) << 4;
      const int4 lo = *(const int4*)(ldsA + r * 128 + p0);
      const int4 hi = *(const int4*)(ldsA + r * 128 + (p0 ^ 16));
      const i32x8 aF = (i32x8){lo.x, lo.y, lo.z, lo.w, hi.x, hi.y, hi.z, hi.w};
      #pragma unroll
      for (int n = 0; n < 4; n++)
        acc[m][n] = __builtin_amdgcn_mfma_scale_f32_16x16x128_f8f6f4(
            aF, bF[n], acc[m][n],
            0, 0,                        // cbsz: A=fp8 e4m3, blgp: B=fp8 e4m3
            0, 0x7F7F7F7F,               // opsel_a, scale_a (unity e8m0)
            0, 0x7F7F7F7F);              // opsel_b, scale_b (unity e8m0)
    }
  }

  // ---- fused epilogue: d = a2[i] + n2[j] - 2*dot; masks; row-min ----
  float n2c[4], thrc[4];
  int tnc[4];
  const int jb = j0 + wc * 64;
  #pragma unroll
  for (int n = 0; n < 4; n++) {
    const int j = jb + n * 16 + lc;
    n2c[n]  = n2[j];
    tnc[n]  = tn[j];
    thrc[n] = dap[j] + MARGIN;   // column-indexed d_ap[j], replicating reference
  }
  #pragma unroll
  for (int m = 0; m < 4; m++) {
    #pragma unroll
    for (int r = 0; r < 4; r++) {
      const int il = wr*64 + m*16 + lg*4 + r;   // C row = (lane>>4)*4 + reg (m89-verified)
      const int i  = i0 + il;
      const float a2i = a2[i];
      const int   tai = ta[i];
      float mv = __uint_as_float(INF_BITS);
      float ms = mv;
      #pragma unroll
      for (int n = 0; n < 4; n++) {
        float d = a2i + n2c[n] - 2.0f * acc[m][n][r];
        bool valid = (tai != tnc[n]);
        if (valid) {
          mv = fminf(mv, d);
          if (d > thrc[n]) ms = fminf(ms, d);
        }
      }
      #pragma unroll
      for (int off = 1; off <= 8; off <<= 1) {  // min over 16-lane column group
        mv = fminf(mv, __shfl_xor(mv, off));
        ms = fminf(ms, __shfl_xor(ms, off));
      }
      if (lc == 0) {   // positive floats: uint order == float order
        atomicMin(&lds_mv[il],  __float_as_uint(mv));
        atomicMin(&lds_msh[il], __float_as_uint(ms));
      }
    }
  }

  __syncthreads();
  if (tid < 128) {
    atomicMin(&gv[i0 + tid],  lds_mv[tid]);
    atomicMin(&gsh[i0 + tid], lds_msh[tid]);
  }
}

// ---------------- Phase 2: d_an select + mean(relu), vectorized ----------------
__global__ __launch_bounds__(256) void finalize_kernel(
    const float* __restrict__ dap, const unsigned* __restrict__ gsh,
    const unsigned* __restrict__ gv, float* __restrict__ out, int n) {
  __shared__ float red[4];
  float s = 0.f;
  const uint4*  g4 = (const uint4*)gsh;
  const uint4*  v4 = (const uint4*)gv;
  const float4* d4 = (const float4*)dap;
  const int nv = n >> 2;
  for (int i = threadIdx.x; i < nv; i += 256) {
    const uint4  us = g4[i];
    const uint4  uv = v4[i];
    const float4 dd = d4[i];
    const unsigned su[4] = {us.x, us.y, us.z, us.w};
    const unsigned vu[4] = {uv.x, uv.y, uv.z, uv.w};
    const float    df[4] = {dd.x, dd.y, dd.z, dd.w};
    #pragma unroll
    for (int e = 0; e < 4; e++) {
      const unsigned b = (su[e] == INF_BITS) ? vu[e] : su[e];   // semihard else hardest
      const float dan = __uint_as_float(b);
      s += fmaxf(df[e] - dan + MARGIN, 0.f);
    }
  }
  #pragma unroll
  for (int off = 32; off > 0; off >>= 1) s += __shfl_down(s, off);
  if ((threadIdx.x & 63) == 0) red[threadIdx.x >> 6] = s;
  __syncthreads();
  if (threadIdx.x == 0) out[0] = (red[0] + red[1] + red[2] + red[3]) / (float)n;
}

extern "C" void kernel_launch(void* const* d_in, const int* in_sizes, int n_in,
                              void* d_out, int out_size, void* d_ws, size_t ws_size,
                              hipStream_t stream) {
  const float* anchor   = (const float*)d_in[0];
  const float* positive = (const float*)d_in[1];
  const float* negative = (const float*)d_in[2];
  const int*   ta       = (const int*)d_in[3];
  const int*   tn       = (const int*)d_in[4];
  const int N = in_sizes[3];
  const int D = in_sizes[0] / N;

  // workspace layout
  unsigned char* a_f8 = (unsigned char*)d_ws;                   // N*D fp8
  unsigned char* n_f8 = a_f8 + (size_t)N * D;                   // N*D fp8
  float* a2  = (float*)(n_f8 + (size_t)N * D);                  // N f32
  float* n2  = a2 + N;
  float* dap = n2 + N;
  unsigned* gsh = (unsigned*)(dap + N);                         // N u32 (min bits)
  unsigned* gv  = gsh + N;
  const size_t needed = (size_t)N * D * 2 + (size_t)N * 20;
  if (ws_size < needed) return;

  const int nj  = N / 128;
  const int nwg = nj * nj;   // 4096 for N=8192; % 8 == 0

  prep_kernel<<<N / 4, 256, 0, stream>>>(anchor, positive, negative,
                                         a_f8, n_f8, a2, n2, dap, gsh, gv, D);
  gemm_min_kernel<<<nwg, 256, 0, stream>>>(a_f8, n_f8, a2, n2, dap,
                                           ta, tn, gsh, gv, D, nj);
  finalize_kernel<<<1, 256, 0, stream>>>(dap, gsh, gv, (float*)d_out, N);
}

// Round 14
// 69.966 us; speedup vs baseline: 2.4519x; 1.2318x over previous
//
#include <hip/hip_runtime.h>
#include <stdint.h>

#define MARGIN 0.2f
#define INF_BITS 0x7F800000u

typedef __attribute__((ext_vector_type(8))) int   i32x8;   // fp8 MFMA operand (32B)
typedef __attribute__((ext_vector_type(4))) float f32x4;

// ---------------- Phase 0: norms, d_ap, fp8 e4m3 conversion, min-init ------------
__global__ __launch_bounds__(256) void prep_kernel(
    const float* __restrict__ anchor, const float* __restrict__ positive,
    const float* __restrict__ negative,
    unsigned char* __restrict__ a_f8, unsigned char* __restrict__ n_f8,
    float* __restrict__ a2, float* __restrict__ n2, float* __restrict__ dap,
    unsigned* __restrict__ gsh, unsigned* __restrict__ gv, int D) {
  const int wid  = threadIdx.x >> 6;
  const int lane = threadIdx.x & 63;
  const int row  = blockIdx.x * 4 + wid;
  const size_t base = (size_t)row * D;
  const int epl = D >> 6;            // elements per lane (8 for D=512)
  const int k0  = lane * epl;
  float sa2 = 0.f, sdap = 0.f, sn2 = 0.f;

  for (int c = 0; c < epl; c += 8) {
    const float4* ap = (const float4*)(anchor   + base + k0 + c);
    const float4* pp = (const float4*)(positive + base + k0 + c);
    const float4* np = (const float4*)(negative + base + k0 + c);
    float4 a0 = ap[0], a1 = ap[1];
    float4 p0 = pp[0], p1 = pp[1];
    float4 v0 = np[0], v1 = np[1];
    float aa[8] = {a0.x,a0.y,a0.z,a0.w,a1.x,a1.y,a1.z,a1.w};
    float pv[8] = {p0.x,p0.y,p0.z,p0.w,p1.x,p1.y,p1.z,p1.w};
    float nn[8] = {v0.x,v0.y,v0.z,v0.w,v1.x,v1.y,v1.z,v1.w};
    #pragma unroll
    for (int e = 0; e < 8; e++) {
      sa2 += aa[e] * aa[e];
      float dd = aa[e] - pv[e];
      sdap += dd * dd;
      sn2 += nn[e] * nn[e];
    }
    unsigned alo = (unsigned)__builtin_amdgcn_cvt_pk_fp8_f32(aa[0], aa[1], 0, false);
    alo          = (unsigned)__builtin_amdgcn_cvt_pk_fp8_f32(aa[2], aa[3], alo, true);
    unsigned ahi = (unsigned)__builtin_amdgcn_cvt_pk_fp8_f32(aa[4], aa[5], 0, false);
    ahi          = (unsigned)__builtin_amdgcn_cvt_pk_fp8_f32(aa[6], aa[7], ahi, true);
    unsigned nlo = (unsigned)__builtin_amdgcn_cvt_pk_fp8_f32(nn[0], nn[1], 0, false);
    nlo          = (unsigned)__builtin_amdgcn_cvt_pk_fp8_f32(nn[2], nn[3], nlo, true);
    unsigned nhi = (unsigned)__builtin_amdgcn_cvt_pk_fp8_f32(nn[4], nn[5], 0, false);
    nhi          = (unsigned)__builtin_amdgcn_cvt_pk_fp8_f32(nn[6], nn[7], nhi, true);
    *(uint2*)(a_f8 + base + k0 + c) = make_uint2(alo, ahi);
    *(uint2*)(n_f8 + base + k0 + c) = make_uint2(nlo, nhi);
  }
  #pragma unroll
  for (int off = 32; off > 0; off >>= 1) {
    sa2  += __shfl_down(sa2,  off);
    sdap += __shfl_down(sdap, off);
    sn2  += __shfl_down(sn2,  off);
  }
  if (lane == 0) {
    a2[row]  = sa2;
    dap[row] = sdap;
    n2[row]  = sn2;
    gsh[row] = INF_BITS;
    gv[row]  = INF_BITS;
  }
}

// ---------------- Phase 1: fp8 MX-MFMA GEMM + fused semihard-min epilogue --------
// R12 GEMM verbatim (77.9 µs, absmax 0.0). R14 epilogue: LDS-transpose reduce,
// collision-free: row slot s = wc*16+lc (waves disjoint by construction),
// stride 32 words (128B/row, pmv fills ldsA exactly). Write XOR key (il&4)?16:0
// (depends only on il -> preserves wave-disjointness; lg groups spread over all
// 32 banks, 2-way = free). Read: thread t reduces row t, 8+8 ds_read_b128 at
// slot q^(t&7) (min is order-independent -> permuted read valid, ~2-way).
__global__ __launch_bounds__(256, 4) void gemm_min_kernel(
    const unsigned char* __restrict__ a_f8, const unsigned char* __restrict__ n_f8,
    const float* __restrict__ a2, const float* __restrict__ n2,
    const float* __restrict__ dap, const int* __restrict__ ta, const int* __restrict__ tn,
    unsigned* __restrict__ gsh, unsigned* __restrict__ gv, int D, int nj) {
  __shared__ unsigned char ldsA[128 * 128];   // [row][128 fp8] = 128B/row, 16KB
  __shared__ unsigned char ldsB[128 * 128];

  const int tid  = threadIdx.x;
  const int lane = tid & 63;
  const int wid  = tid >> 6;
  const int wr   = wid >> 1, wc = wid & 1;   // 2x2 wave grid, 64x64 per wave
  const int lg   = lane >> 4;                // 0..3 (K-block of 32 within frag)
  const int lc   = lane & 15;                // 0..15 (row within frag)

  // ---- 2D-chunked XCD swizzle (R6-proven) ----
  const int bid = (int)blockIdx.x;
  int it, jt;
  if ((nj & 7) == 0) {
    const int band = nj >> 3;
    const int xcd  = bid & 7;
    const int l    = bid >> 3;
    const int q    = l / (band * 8);
    const int s    = l - q * (band * 8);
    it = xcd * band + (s >> 3);
    jt = q * 8 + (s & 7);
  } else {
    const int wg = (bid & 7) * ((int)gridDim.x >> 3) + (bid >> 3);
    it = wg / nj; jt = wg % nj;
  }
  const int i0 = it * 128;
  const int j0 = jt * 128;

  // staging: 8 gload_lds instrs (4 A + 4 B); instr c, wave wid covers rows
  // c*32 + wid*8 + (lane>>3), phys slot lane&7, src col = (slot^(row&7))*16B.
  const int srow8 = lane >> 3;
  const int scolB = ((lane & 7) ^ srow8) << 4;
  unsigned aBase[4], bBase[4];
  #pragma unroll
  for (int c = 0; c < 4; c++) {
    const int ro = c * 32 + wid * 8 + srow8;
    aBase[c] = (unsigned)((i0 + ro) * D + scolB);
    bBase[c] = (unsigned)((j0 + ro) * D + scolB);
  }

  f32x4 acc[4][4];
  #pragma unroll
  for (int m = 0; m < 4; m++)
    #pragma unroll
    for (int n = 0; n < 4; n++)
      acc[m][n] = (f32x4){0.f, 0.f, 0.f, 0.f};

  const int nt = D >> 7;   // 4 K-steps of 128

  for (int t = 0; t < nt; ++t) {
    const int kc = t << 7;
    __syncthreads();
    #pragma unroll
    for (int c = 0; c < 4; c++) {
      __builtin_amdgcn_global_load_lds(
          (const __attribute__((address_space(1))) void*)(a_f8 + aBase[c] + kc),
          (__attribute__((address_space(3))) void*)(ldsA + c * 4096 + wid * 1024),
          16, 0, 0);
      __builtin_amdgcn_global_load_lds(
          (const __attribute__((address_space(1))) void*)(n_f8 + bBase[c] + kc),
          (__attribute__((address_space(3))) void*)(ldsB + c * 4096 + wid * 1024),
          16, 0, 0);
    }
    __syncthreads();

    i32x8 bF[4];
    #pragma unroll
    for (int n = 0; n < 4; n++) {
      const int r  = wc * 64 + n * 16 + lc;
      const int p0 = ((lg << 1) ^ (r & 7)) << 4;        // p1 = p0 ^ 16
      const int4 lo = *(const int4*)(ldsB + r * 128 + p0);
      const int4 hi = *(const int4*)(ldsB + r * 128 + (p0 ^ 16));
      bF[n] = (i32x8){lo.x, lo.y, lo.z, lo.w, hi.x, hi.y, hi.z, hi.w};
    }
    #pragma unroll
    for (int m = 0; m < 4; m++) {
      const int r  = wr * 64 + m * 16 + lc;
      const int p0 = ((lg << 1) ^ (r & 7)) << 4;
      const int4 lo = *(const int4*)(ldsA + r * 128 + p0);
      const int4 hi = *(const int4*)(ldsA + r * 128 + (p0 ^ 16));
      const i32x8 aF = (i32x8){lo.x, lo.y, lo.z, lo.w, hi.x, hi.y, hi.z, hi.w};
      #pragma unroll
      for (int n = 0; n < 4; n++)
        acc[m][n] = __builtin_amdgcn_mfma_scale_f32_16x16x128_f8f6f4(
            aF, bF[n], acc[m][n],
            0, 0,                        // cbsz/blgp: fp8 e4m3 both
            0, 0x7F7F7F7F,               // opsel_a, scale_a (unity e8m0)
            0, 0x7F7F7F7F);              // opsel_b, scale_b (unity e8m0)
    }
  }

  // ---- fused epilogue v3: collision-free LDS-transpose reduce ----
  __syncthreads();   // tiles dead
  unsigned* pmv = (unsigned*)ldsA;   // [128][32] u32 = 16KB exactly
  unsigned* pms = (unsigned*)ldsB;

  float n2c[4], thrc[4];
  int tnc[4];
  const int jb = j0 + wc * 64;
  #pragma unroll
  for (int n = 0; n < 4; n++) {
    const int j = jb + n * 16 + lc;
    n2c[n]  = n2[j];
    tnc[n]  = tn[j];
    thrc[n] = dap[j] + MARGIN;   // column-indexed d_ap[j], replicating reference
  }
  const int sbase = wc * 16 + lc;   // per-wave-disjoint slot within row
  #pragma unroll
  for (int m = 0; m < 4; m++) {
    #pragma unroll
    for (int r = 0; r < 4; r++) {
      const int il = wr*64 + m*16 + lg*4 + r;   // C row = (lane>>4)*4 + reg
      const int i  = i0 + il;
      const float a2i = a2[i];
      const int   tai = ta[i];
      float mv = __uint_as_float(INF_BITS);
      float ms = mv;
      #pragma unroll
      for (int n = 0; n < 4; n++) {
        float d = a2i + n2c[n] - 2.0f * acc[m][n][r];
        bool valid = (tai != tnc[n]);
        if (valid) {
          mv = fminf(mv, d);
          if (d > thrc[n]) ms = fminf(ms, d);
        }
      }
      const int sw = sbase ^ ((il & 4) ? 16 : 0);   // bank spread, il-only key
      pmv[il * 32 + sw] = __float_as_uint(mv);
      pms[il * 32 + sw] = __float_as_uint(ms);
    }
  }
  __syncthreads();

  if (tid < 128) {
    unsigned mv = 0xFFFFFFFFu, ms = 0xFFFFFFFFu;
    #pragma unroll
    for (int q = 0; q < 8; q++) {
      const int sl = (q ^ (tid & 7)) << 2;          // XOR-read: ~2-way banks
      const uint4 a = *(const uint4*)(pmv + tid * 32 + sl);
      const uint4 b = *(const uint4*)(pms + tid * 32 + sl);
      mv = min(mv, min(min(a.x, a.y), min(a.z, a.w)));
      ms = min(ms, min(min(b.x, b.y), min(b.z, b.w)));
    }
    // positive-float bits: uint order == float order
    atomicMin(&gv[i0 + tid],  mv);
    atomicMin(&gsh[i0 + tid], ms);
  }
}

// ---------------- Phase 2: d_an select + mean(relu), vectorized ----------------
__global__ __launch_bounds__(256) void finalize_kernel(
    const float* __restrict__ dap, const unsigned* __restrict__ gsh,
    const unsigned* __restrict__ gv, float* __restrict__ out, int n) {
  __shared__ float red[4];
  float s = 0.f;
  const uint4*  g4 = (const uint4*)gsh;
  const uint4*  v4 = (const uint4*)gv;
  const float4* d4 = (const float4*)dap;
  const int nv = n >> 2;
  for (int i = threadIdx.x; i < nv; i += 256) {
    const uint4  us = g4[i];
    const uint4  uv = v4[i];
    const float4 dd = d4[i];
    const unsigned su[4] = {us.x, us.y, us.z, us.w};
    const unsigned vu[4] = {uv.x, uv.y, uv.z, uv.w};
    const float    df[4] = {dd.x, dd.y, dd.z, dd.w};
    #pragma unroll
    for (int e = 0; e < 4; e++) {
      const unsigned b = (su[e] == INF_BITS) ? vu[e] : su[e];
      const float dan = __uint_as_float(b);
      s += fmaxf(df[e] - dan + MARGIN, 0.f);
    }
  }
  #pragma unroll
  for (int off = 32; off > 0; off >>= 1) s += __shfl_down(s, off);
  if ((threadIdx.x & 63) == 0) red[threadIdx.x >> 6] = s;
  __syncthreads();
  if (threadIdx.x == 0) out[0] = (red[0] + red[1] + red[2] + red[3]) / (float)n;
}

extern "C" void kernel_launch(void* const* d_in, const int* in_sizes, int n_in,
                              void* d_out, int out_size, void* d_ws, size_t ws_size,
                              hipStream_t stream) {
  const float* anchor   = (const float*)d_in[0];
  const float* positive = (const float*)d_in[1];
  const float* negative = (const float*)d_in[2];
  const int*   ta       = (const int*)d_in[3];
  const int*   tn       = (const int*)d_in[4];
  const int N = in_sizes[3];
  const int D = in_sizes[0] / N;

  unsigned char* a_f8 = (unsigned char*)d_ws;                   // N*D fp8
  unsigned char* n_f8 = a_f8 + (size_t)N * D;                   // N*D fp8
  float* a2  = (float*)(n_f8 + (size_t)N * D);                  // N f32
  float* n2  = a2 + N;
  float* dap = n2 + N;
  unsigned* gsh = (unsigned*)(dap + N);                         // N u32 (min bits)
  unsigned* gv  = gsh + N;
  const size_t needed = (size_t)N * D * 2 + (size_t)N * 20;
  if (ws_size < needed) return;

  const int nj  = N / 128;
  const int nwg = nj * nj;   // 4096 for N=8192; % 8 == 0

  prep_kernel<<<N / 4, 256, 0, stream>>>(anchor, positive, negative,
                                         a_f8, n_f8, a2, n2, dap, gsh, gv, D);
  gemm_min_kernel<<<nwg, 256, 0, stream>>>(a_f8, n_f8, a2, n2, dap,
                                           ta, tn, gsh, gv, D, nj);
  finalize_kernel<<<1, 256, 0, stream>>>(dap, gsh, gv, (float*)d_out, N);
}